// Round 5
// baseline (134.494 us; speedup 1.0000x reference)
//
#include <hip/hip_runtime.h>

#define N_NODES 50000
#define K_DEG   17
#define DIN     128
#define DOUT    64

typedef __attribute__((ext_vector_type(8))) short  short8;   // bf16 A/B frag (4 VGPR)
typedef __attribute__((ext_vector_type(4))) float  floatx4;  // C/D frag

// ---------------------------------------------------------------------------
// Batcher merge-exchange sorting network (compile-time; fully unrolls).
// ---------------------------------------------------------------------------
struct CEPair { unsigned char a, b; };

constexpr int net_count(int n) {
  int t = 0; while ((1 << t) < n) ++t;
  int cnt = 0;
  for (int p = 1 << (t - 1); p > 0; p >>= 1) {
    int q = 1 << (t - 1), r = 0, d = p;
    for (;;) {
      for (int i = 0; i < n - d; ++i)
        if ((i & p) == r) ++cnt;
      if (q == p) break;
      d = q - p; q >>= 1; r = p;
    }
  }
  return cnt;
}

template <int NP> struct NetArr { CEPair v[NP]; };

template <int NP>
constexpr NetArr<NP> net_pairs(int n) {
  NetArr<NP> out{};
  int t = 0; while ((1 << t) < n) ++t;
  int cnt = 0;
  for (int p = 1 << (t - 1); p > 0; p >>= 1) {
    int q = 1 << (t - 1), r = 0, d = p;
    for (;;) {
      for (int i = 0; i < n - d; ++i)
        if ((i & p) == r) {
          out.v[cnt].a = (unsigned char)i;
          out.v[cnt].b = (unsigned char)(i + d);
          ++cnt;
        }
      if (q == p) break;
      d = q - p; q >>= 1; r = p;
    }
  }
  return out;
}

constexpr int NP17 = net_count(K_DEG);   // 74 compare-exchanges for n=17

// ---------------------------------------------------------------------------
// bf16 helpers (RNE)
// ---------------------------------------------------------------------------
__device__ __forceinline__ unsigned int f2bf(float f) {
  union { float f; unsigned int u; } c; c.f = f;
  return (c.u + 0x7FFFu + ((c.u >> 16) & 1u)) >> 16;
}
__device__ __forceinline__ float bf2f(unsigned int b) {
  union { float f; unsigned int u; } c; c.u = b << 16;
  return c.f;
}

// ---------------------------------------------------------------------------
// Kernel 0: convert W -> frag-ordered bf16 hi/lo table T (32 KB total).
// T[((ks*4+nt)*64 + lane)*8 + j] = bf16( W[k*DOUT+n] ),
//   k = ks*32 + (lane>>4)*8 + j,  n = nt*16 + (lane&15).  (R3/R4-verified)
// ---------------------------------------------------------------------------
__global__ void convw_kernel(const float* __restrict__ W,
                             unsigned short* __restrict__ T) {
  const int flat = blockIdx.x * 256 + threadIdx.x;   // 0..8191
  const int j    = flat & 7;
  const int lane = (flat >> 3) & 63;
  const int pair = flat >> 9;                        // 0..15
  const int ks   = pair >> 2, nt = pair & 3;
  const int k    = ks * 32 + (lane >> 4) * 8 + j;
  const int n    = nt * 16 + (lane & 15);
  const float f  = W[k * DOUT + n];
  const unsigned int hb = f2bf(f);
  const float        lo = f - bf2f(hb);
  const unsigned int lb = f2bf(lo);
  T[flat]        = (unsigned short)hb;
  T[flat + 8192] = (unsigned short)lb;
}

// ---------------------------------------------------------------------------
// Kernel 1: xp = x @ W via bf16 MFMA, 3-term hi/lo split. No LDS/barrier;
// B-frags from L1-resident table T, A direct from global (x read once).
// Near its 38.4MB memory floor (R3->R4 restructure was neutral) — frozen.
// ---------------------------------------------------------------------------
__global__ __launch_bounds__(256) void gemm_kernel(
    const float* __restrict__ x, const unsigned short* __restrict__ T,
    float* __restrict__ xp) {
  const int gwave = blockIdx.x * 4 + (threadIdx.x >> 6);
  if (gwave >= (N_NODES / 16)) return;
  const int lane = threadIdx.x & 63;
  const int r0 = gwave * 16;
  const int m  = lane & 15;     // A row within tile
  const int q  = lane >> 4;     // k-quad

  const float4* x4 = (const float4*)x;
  float4 xr[8];
  #pragma unroll
  for (int ks = 0; ks < 4; ++ks) {
    const int base = (r0 + m) * (DIN / 4) + ks * 8 + q * 2;
    xr[ks * 2 + 0] = x4[base + 0];
    xr[ks * 2 + 1] = x4[base + 1];
  }

  floatx4 acc[4];
  #pragma unroll
  for (int nt = 0; nt < 4; ++nt) acc[nt] = (floatx4){0.f, 0.f, 0.f, 0.f};

  const short8* Th = (const short8*)T;
  const short8* Tl = (const short8*)(T + 8192);

  #pragma unroll
  for (int ks = 0; ks < 4; ++ks) {
    short8 Bh[4], Bl[4];
    #pragma unroll
    for (int nt = 0; nt < 4; ++nt) {
      const int fi = (ks * 4 + nt) * 64 + lane;
      Bh[nt] = Th[fi];
      Bl[nt] = Tl[fi];
    }
    float f[8] = {xr[ks*2].x, xr[ks*2].y, xr[ks*2].z, xr[ks*2].w,
                  xr[ks*2+1].x, xr[ks*2+1].y, xr[ks*2+1].z, xr[ks*2+1].w};
    union { unsigned int i[4]; short8 s; } Ah, Al;
    #pragma unroll
    for (int r = 0; r < 4; ++r) {
      const unsigned int h0 = f2bf(f[2*r]),   h1 = f2bf(f[2*r+1]);
      const unsigned int l0 = f2bf(f[2*r]   - bf2f(h0));
      const unsigned int l1 = f2bf(f[2*r+1] - bf2f(h1));
      Ah.i[r] = h0 | (h1 << 16);
      Al.i[r] = l0 | (l1 << 16);
    }
    #pragma unroll
    for (int nt = 0; nt < 4; ++nt) {
      acc[nt] = __builtin_amdgcn_mfma_f32_16x16x32_bf16(Al.s, Bh[nt], acc[nt], 0, 0, 0);
      acc[nt] = __builtin_amdgcn_mfma_f32_16x16x32_bf16(Ah.s, Bl[nt], acc[nt], 0, 0, 0);
      acc[nt] = __builtin_amdgcn_mfma_f32_16x16x32_bf16(Ah.s, Bh[nt], acc[nt], 0, 0, 0);
    }
  }

  #pragma unroll
  for (int nt = 0; nt < 4; ++nt) {
    const int col = nt * 16 + m;
    #pragma unroll
    for (int r = 0; r < 4; ++r)
      xp[(r0 + q * 4 + r) * DOUT + col] = acc[nt][r];
  }
}

// ---------------------------------------------------------------------------
// Kernel 2: per-node per-dim weighted median + row_sum scale + bias.
// VALU-bound (80%+). This round: explicit fminf/fmaxf CEs, 32-bit uint
// gather offsets, deeper load pipelining, hoisted bias.
// Summation order replicates reference exactly: cumsum sequential in sorted
// order, total = last cum, row_sum in original edge order.
// ---------------------------------------------------------------------------
__global__ __launch_bounds__(256) void median_kernel(
    const float* __restrict__ xp, const int* __restrict__ col,
    const float* __restrict__ ew, const float* __restrict__ bias,
    float* __restrict__ out) {
  const int wave = threadIdx.x >> 6;
  const int lane = threadIdx.x & 63;
  const int node = blockIdx.x * 4 + wave;
  if (node >= N_NODES) return;

  const int*   cp = col + node * K_DEG;
  const float* wp = ew  + node * K_DEG;

  // 1) neighbor ids
  int ci[K_DEG];
  #pragma unroll
  for (int j = 0; j < K_DEG; ++j) ci[j] = cp[j];

  // 2) gathers: uniform base + 32-bit offset (global_load v,voff,s[base])
  float v[K_DEG];
  #pragma unroll
  for (int j = 0; j < K_DEG; ++j) {
    const unsigned off = (unsigned)(ci[j] * DOUT + lane);
    v[j] = xp[off];                   // 256B coalesced row gather
  }

  // 3) weights + bias (latency hidden under the sort)
  float w[K_DEG];
  #pragma unroll
  for (int j = 0; j < K_DEG; ++j) w[j] = wp[j];
  const float bl = bias[lane];

  // row_sum: original edge order (matches segment_sum)
  float rs = 0.f;
  #pragma unroll
  for (int j = 0; j < K_DEG; ++j) rs += w[j];

  // sort (v,w) pairs by v ascending — compile-time Batcher network.
  // CE = v_cmp + v_min + v_max + 2*v_cndmask (5 VALU ops).
  constexpr NetArr<NP17> NET = net_pairs<NP17>(K_DEG);
  #pragma unroll
  for (int s = 0; s < NP17; ++s) {
    const int a = NET.v[s].a, b = NET.v[s].b;
    const float va = v[a], vb = v[b];
    const bool  sw = vb < va;
    const float lo = fminf(va, vb), hi = fmaxf(va, vb);
    const float wa = w[a], wb = w[b];
    v[a] = lo;            v[b] = hi;
    w[a] = sw ? wb : wa;  w[b] = sw ? wa : wb;
  }

  // sequential cumsum in sorted order (exact reference order)
  float c[K_DEG];
  float run = 0.f;
  #pragma unroll
  for (int j = 0; j < K_DEG; ++j) { run += w[j]; c[j] = run; }
  const float half = 0.5f * run;

  // first sorted position with cum >= half: backward cndmask scan
  float med = v[K_DEG - 1];
  #pragma unroll
  for (int j = K_DEG - 2; j >= 0; --j)
    med = (c[j] >= half) ? v[j] : med;

  out[node * DOUT + lane] = rs * med + bl;
}

// ---------------------------------------------------------------------------
extern "C" void kernel_launch(void* const* d_in, const int* in_sizes, int n_in,
                              void* d_out, int out_size, void* d_ws, size_t ws_size,
                              hipStream_t stream) {
  const float* x    = (const float*)d_in[0];
  const int*   ei   = (const int*)d_in[1];
  const float* ew   = (const float*)d_in[2];
  const float* W    = (const float*)d_in[3];
  const float* bias = (const float*)d_in[4];
  float*       out  = (float*)d_out;

  float*          xp = (float*)d_ws;                            // 12.8 MB
  unsigned short* T  = (unsigned short*)((char*)d_ws + (size_t)N_NODES * DOUT * 4);
  const int*      colp = ei + (size_t)N_NODES * K_DEG;          // edge_index[1]

  convw_kernel<<<8192 / 256, 256, 0, stream>>>(W, T);
  gemm_kernel<<<(N_NODES / 16 + 3) / 4, 256, 0, stream>>>(x, T, xp);
  median_kernel<<<(N_NODES + 3) / 4, 256, 0, stream>>>(xp, colp, ew, bias, out);
}

// Round 6
// 132.398 us; speedup vs baseline: 1.0158x; 1.0158x over previous
//
#include <hip/hip_runtime.h>

#define N_NODES 50000
#define K_DEG   17
#define DIN     128
#define DOUT    64

typedef __attribute__((ext_vector_type(8))) short  short8;   // bf16 A/B frag (4 VGPR)
typedef __attribute__((ext_vector_type(4))) float  floatx4;  // C/D frag

// ---------------------------------------------------------------------------
// Batcher merge-exchange sorting network (compile-time; fully unrolls).
// ---------------------------------------------------------------------------
struct CEPair { unsigned char a, b; };

constexpr int net_count(int n) {
  int t = 0; while ((1 << t) < n) ++t;
  int cnt = 0;
  for (int p = 1 << (t - 1); p > 0; p >>= 1) {
    int q = 1 << (t - 1), r = 0, d = p;
    for (;;) {
      for (int i = 0; i < n - d; ++i)
        if ((i & p) == r) ++cnt;
      if (q == p) break;
      d = q - p; q >>= 1; r = p;
    }
  }
  return cnt;
}

template <int NP> struct NetArr { CEPair v[NP]; };

template <int NP>
constexpr NetArr<NP> net_pairs(int n) {
  NetArr<NP> out{};
  int t = 0; while ((1 << t) < n) ++t;
  int cnt = 0;
  for (int p = 1 << (t - 1); p > 0; p >>= 1) {
    int q = 1 << (t - 1), r = 0, d = p;
    for (;;) {
      for (int i = 0; i < n - d; ++i)
        if ((i & p) == r) {
          out.v[cnt].a = (unsigned char)i;
          out.v[cnt].b = (unsigned char)(i + d);
          ++cnt;
        }
      if (q == p) break;
      d = q - p; q >>= 1; r = p;
    }
  }
  return out;
}

constexpr int NP17 = net_count(K_DEG);   // 74 compare-exchanges for n=17

// ---------------------------------------------------------------------------
// bf16 helpers (RNE)
// ---------------------------------------------------------------------------
__device__ __forceinline__ unsigned int f2bf(float f) {
  union { float f; unsigned int u; } c; c.f = f;
  return (c.u + 0x7FFFu + ((c.u >> 16) & 1u)) >> 16;
}
__device__ __forceinline__ float bf2f(unsigned int b) {
  union { float f; unsigned int u; } c; c.u = b << 16;
  return c.f;
}

// ---------------------------------------------------------------------------
// Kernel 0: convert W -> frag-ordered bf16 hi/lo table T (32 KB total).
// T[((ks*4+nt)*64 + lane)*8 + j] = bf16( W[k*DOUT+n] ),
//   k = ks*32 + (lane>>4)*8 + j,  n = nt*16 + (lane&15).  (R3/R4-verified)
// ---------------------------------------------------------------------------
__global__ void convw_kernel(const float* __restrict__ W,
                             unsigned short* __restrict__ T) {
  const int flat = blockIdx.x * 256 + threadIdx.x;   // 0..8191
  const int j    = flat & 7;
  const int lane = (flat >> 3) & 63;
  const int pair = flat >> 9;                        // 0..15
  const int ks   = pair >> 2, nt = pair & 3;
  const int k    = ks * 32 + (lane >> 4) * 8 + j;
  const int n    = nt * 16 + (lane & 15);
  const float f  = W[k * DOUT + n];
  const unsigned int hb = f2bf(f);
  const float        lo = f - bf2f(hb);
  const unsigned int lb = f2bf(lo);
  T[flat]        = (unsigned short)hb;
  T[flat + 8192] = (unsigned short)lb;
}

// ---------------------------------------------------------------------------
// Kernel 1: xp = x @ W via bf16 MFMA, 3-term hi/lo split. No LDS/barrier;
// B-frags from L1-resident table T, A direct from global (x read once).
// Near its 38.4MB memory floor — frozen since R4.
// ---------------------------------------------------------------------------
__global__ __launch_bounds__(256) void gemm_kernel(
    const float* __restrict__ x, const unsigned short* __restrict__ T,
    float* __restrict__ xp) {
  const int gwave = blockIdx.x * 4 + (threadIdx.x >> 6);
  if (gwave >= (N_NODES / 16)) return;
  const int lane = threadIdx.x & 63;
  const int r0 = gwave * 16;
  const int m  = lane & 15;     // A row within tile
  const int q  = lane >> 4;     // k-quad

  const float4* x4 = (const float4*)x;
  float4 xr[8];
  #pragma unroll
  for (int ks = 0; ks < 4; ++ks) {
    const int base = (r0 + m) * (DIN / 4) + ks * 8 + q * 2;
    xr[ks * 2 + 0] = x4[base + 0];
    xr[ks * 2 + 1] = x4[base + 1];
  }

  floatx4 acc[4];
  #pragma unroll
  for (int nt = 0; nt < 4; ++nt) acc[nt] = (floatx4){0.f, 0.f, 0.f, 0.f};

  const short8* Th = (const short8*)T;
  const short8* Tl = (const short8*)(T + 8192);

  #pragma unroll
  for (int ks = 0; ks < 4; ++ks) {
    short8 Bh[4], Bl[4];
    #pragma unroll
    for (int nt = 0; nt < 4; ++nt) {
      const int fi = (ks * 4 + nt) * 64 + lane;
      Bh[nt] = Th[fi];
      Bl[nt] = Tl[fi];
    }
    float f[8] = {xr[ks*2].x, xr[ks*2].y, xr[ks*2].z, xr[ks*2].w,
                  xr[ks*2+1].x, xr[ks*2+1].y, xr[ks*2+1].z, xr[ks*2+1].w};
    union { unsigned int i[4]; short8 s; } Ah, Al;
    #pragma unroll
    for (int r = 0; r < 4; ++r) {
      const unsigned int h0 = f2bf(f[2*r]),   h1 = f2bf(f[2*r+1]);
      const unsigned int l0 = f2bf(f[2*r]   - bf2f(h0));
      const unsigned int l1 = f2bf(f[2*r+1] - bf2f(h1));
      Ah.i[r] = h0 | (h1 << 16);
      Al.i[r] = l0 | (l1 << 16);
    }
    #pragma unroll
    for (int nt = 0; nt < 4; ++nt) {
      acc[nt] = __builtin_amdgcn_mfma_f32_16x16x32_bf16(Al.s, Bh[nt], acc[nt], 0, 0, 0);
      acc[nt] = __builtin_amdgcn_mfma_f32_16x16x32_bf16(Ah.s, Bl[nt], acc[nt], 0, 0, 0);
      acc[nt] = __builtin_amdgcn_mfma_f32_16x16x32_bf16(Ah.s, Bh[nt], acc[nt], 0, 0, 0);
    }
  }

  #pragma unroll
  for (int nt = 0; nt < 4; ++nt) {
    const int col = nt * 16 + m;
    #pragma unroll
    for (int r = 0; r < 4; ++r)
      xp[(r0 + q * 4 + r) * DOUT + col] = acc[nt][r];
  }
}

// ---------------------------------------------------------------------------
// Kernel 2: per-node per-dim weighted median + row_sum scale + bias.
// R3-exact body (best measured). __launch_bounds__(256,2) lifts the VGPR
// cap: live set (v[17]+w[17]/c[17]+temps ~40+) no longer gets squeezed to
// 28-36 regs (R5 showed tighter regs -> MORE instructions -> slower).
// Summation order replicates reference exactly: cumsum sequential in sorted
// order, total = last cum, row_sum in original edge order.
// ---------------------------------------------------------------------------
__global__ __launch_bounds__(256, 2) void median_kernel(
    const float* __restrict__ xp, const int* __restrict__ col,
    const float* __restrict__ ew, const float* __restrict__ bias,
    float* __restrict__ out) {
  const int wave = threadIdx.x >> 6;
  const int lane = threadIdx.x & 63;
  const int node = blockIdx.x * 4 + wave;
  if (node >= N_NODES) return;

  const int*   cp = col + node * K_DEG;
  const float* wp = ew  + node * K_DEG;

  float v[K_DEG], w[K_DEG];
  #pragma unroll
  for (int j = 0; j < K_DEG; ++j) {
    int c = cp[j];
    v[j] = xp[c * DOUT + lane];       // 256B coalesced gather, pipelined
    w[j] = wp[j];
  }

  // row_sum: original edge order (matches segment_sum)
  float rs = 0.f;
  #pragma unroll
  for (int j = 0; j < K_DEG; ++j) rs += w[j];

  // sort (v,w) pairs by v ascending — compile-time Batcher network
  constexpr NetArr<NP17> NET = net_pairs<NP17>(K_DEG);
  #pragma unroll
  for (int s = 0; s < NP17; ++s) {
    const int a = NET.v[s].a, b = NET.v[s].b;
    float va = v[a], vb = v[b];
    bool sw = vb < va;
    float wa = w[a], wb = w[b];
    v[a] = sw ? vb : va;  v[b] = sw ? va : vb;
    w[a] = sw ? wb : wa;  w[b] = sw ? wa : wb;
  }

  // sequential cumsum in sorted order (exact reference order)
  float c[K_DEG];
  float run = 0.f;
  #pragma unroll
  for (int j = 0; j < K_DEG; ++j) { run += w[j]; c[j] = run; }
  const float half = 0.5f * run;

  // first sorted position with cum >= half: backward cndmask scan
  float med = v[K_DEG - 1];
  #pragma unroll
  for (int j = K_DEG - 2; j >= 0; --j)
    med = (c[j] >= half) ? v[j] : med;

  out[node * DOUT + lane] = rs * med + bias[lane];
}

// ---------------------------------------------------------------------------
extern "C" void kernel_launch(void* const* d_in, const int* in_sizes, int n_in,
                              void* d_out, int out_size, void* d_ws, size_t ws_size,
                              hipStream_t stream) {
  const float* x    = (const float*)d_in[0];
  const int*   ei   = (const int*)d_in[1];
  const float* ew   = (const float*)d_in[2];
  const float* W    = (const float*)d_in[3];
  const float* bias = (const float*)d_in[4];
  float*       out  = (float*)d_out;

  float*          xp = (float*)d_ws;                            // 12.8 MB
  unsigned short* T  = (unsigned short*)((char*)d_ws + (size_t)N_NODES * DOUT * 4);
  const int*      colp = ei + (size_t)N_NODES * K_DEG;          // edge_index[1]

  convw_kernel<<<8192 / 256, 256, 0, stream>>>(W, T);
  gemm_kernel<<<(N_NODES / 16 + 3) / 4, 256, 0, stream>>>(x, T, xp);
  median_kernel<<<(N_NODES + 3) / 4, 256, 0, stream>>>(xp, colp, ew, bias, out);
}

// Round 7
// 125.356 us; speedup vs baseline: 1.0729x; 1.0562x over previous
//
#include <hip/hip_runtime.h>

#define N_NODES 50000
#define K_DEG   17
#define DIN     128
#define DOUT    64

typedef __attribute__((ext_vector_type(8))) short  short8;   // bf16 A/B frag (4 VGPR)
typedef __attribute__((ext_vector_type(4))) float  floatx4;  // C/D frag

// ---------------------------------------------------------------------------
// Batcher merge-exchange sorting network (compile-time; fully unrolls).
// ---------------------------------------------------------------------------
struct CEPair { unsigned char a, b; };

constexpr int net_count(int n) {
  int t = 0; while ((1 << t) < n) ++t;
  int cnt = 0;
  for (int p = 1 << (t - 1); p > 0; p >>= 1) {
    int q = 1 << (t - 1), r = 0, d = p;
    for (;;) {
      for (int i = 0; i < n - d; ++i)
        if ((i & p) == r) ++cnt;
      if (q == p) break;
      d = q - p; q >>= 1; r = p;
    }
  }
  return cnt;
}

template <int NP> struct NetArr { CEPair v[NP]; };

template <int NP>
constexpr NetArr<NP> net_pairs(int n) {
  NetArr<NP> out{};
  int t = 0; while ((1 << t) < n) ++t;
  int cnt = 0;
  for (int p = 1 << (t - 1); p > 0; p >>= 1) {
    int q = 1 << (t - 1), r = 0, d = p;
    for (;;) {
      for (int i = 0; i < n - d; ++i)
        if ((i & p) == r) {
          out.v[cnt].a = (unsigned char)i;
          out.v[cnt].b = (unsigned char)(i + d);
          ++cnt;
        }
      if (q == p) break;
      d = q - p; q >>= 1; r = p;
    }
  }
  return out;
}

constexpr int NP17 = net_count(K_DEG);   // 74 compare-exchanges for n=17

// ---------------------------------------------------------------------------
// bf16 helpers (RNE)
// ---------------------------------------------------------------------------
__device__ __forceinline__ unsigned int f2bf(float f) {
  union { float f; unsigned int u; } c; c.f = f;
  return (c.u + 0x7FFFu + ((c.u >> 16) & 1u)) >> 16;
}
__device__ __forceinline__ float bf2f(unsigned int b) {
  union { float f; unsigned int u; } c; c.u = b << 16;
  return c.f;
}

// ---------------------------------------------------------------------------
// Kernel 0: convert W -> frag-ordered bf16 hi/lo table T (32 KB). Frozen.
// T[((ks*4+nt)*64 + lane)*8 + j] = bf16( W[k*DOUT+n] ),
//   k = ks*32 + (lane>>4)*8 + j,  n = nt*16 + (lane&15).
// ---------------------------------------------------------------------------
__global__ void convw_kernel(const float* __restrict__ W,
                             unsigned short* __restrict__ T) {
  const int flat = blockIdx.x * 256 + threadIdx.x;   // 0..8191
  const int j    = flat & 7;
  const int lane = (flat >> 3) & 63;
  const int pair = flat >> 9;                        // 0..15
  const int ks   = pair >> 2, nt = pair & 3;
  const int k    = ks * 32 + (lane >> 4) * 8 + j;
  const int n    = nt * 16 + (lane & 15);
  const float f  = W[k * DOUT + n];
  const unsigned int hb = f2bf(f);
  const float        lo = f - bf2f(hb);
  const unsigned int lb = f2bf(lo);
  T[flat]        = (unsigned short)hb;
  T[flat + 8192] = (unsigned short)lb;
}

// ---------------------------------------------------------------------------
// Kernel 1: xp = x @ W via bf16 MFMA, 3-term hi/lo split. Frozen since R4
// (near its 38.4MB memory floor).
// ---------------------------------------------------------------------------
__global__ __launch_bounds__(256) void gemm_kernel(
    const float* __restrict__ x, const unsigned short* __restrict__ T,
    float* __restrict__ xp) {
  const int gwave = blockIdx.x * 4 + (threadIdx.x >> 6);
  if (gwave >= (N_NODES / 16)) return;
  const int lane = threadIdx.x & 63;
  const int r0 = gwave * 16;
  const int m  = lane & 15;     // A row within tile
  const int q  = lane >> 4;     // k-quad

  const float4* x4 = (const float4*)x;
  float4 xr[8];
  #pragma unroll
  for (int ks = 0; ks < 4; ++ks) {
    const int base = (r0 + m) * (DIN / 4) + ks * 8 + q * 2;
    xr[ks * 2 + 0] = x4[base + 0];
    xr[ks * 2 + 1] = x4[base + 1];
  }

  floatx4 acc[4];
  #pragma unroll
  for (int nt = 0; nt < 4; ++nt) acc[nt] = (floatx4){0.f, 0.f, 0.f, 0.f};

  const short8* Th = (const short8*)T;
  const short8* Tl = (const short8*)(T + 8192);

  #pragma unroll
  for (int ks = 0; ks < 4; ++ks) {
    short8 Bh[4], Bl[4];
    #pragma unroll
    for (int nt = 0; nt < 4; ++nt) {
      const int fi = (ks * 4 + nt) * 64 + lane;
      Bh[nt] = Th[fi];
      Bl[nt] = Tl[fi];
    }
    float f[8] = {xr[ks*2].x, xr[ks*2].y, xr[ks*2].z, xr[ks*2].w,
                  xr[ks*2+1].x, xr[ks*2+1].y, xr[ks*2+1].z, xr[ks*2+1].w};
    union { unsigned int i[4]; short8 s; } Ah, Al;
    #pragma unroll
    for (int r = 0; r < 4; ++r) {
      const unsigned int h0 = f2bf(f[2*r]),   h1 = f2bf(f[2*r+1]);
      const unsigned int l0 = f2bf(f[2*r]   - bf2f(h0));
      const unsigned int l1 = f2bf(f[2*r+1] - bf2f(h1));
      Ah.i[r] = h0 | (h1 << 16);
      Al.i[r] = l0 | (l1 << 16);
    }
    #pragma unroll
    for (int nt = 0; nt < 4; ++nt) {
      acc[nt] = __builtin_amdgcn_mfma_f32_16x16x32_bf16(Al.s, Bh[nt], acc[nt], 0, 0, 0);
      acc[nt] = __builtin_amdgcn_mfma_f32_16x16x32_bf16(Ah.s, Bl[nt], acc[nt], 0, 0, 0);
      acc[nt] = __builtin_amdgcn_mfma_f32_16x16x32_bf16(Ah.s, Bh[nt], acc[nt], 0, 0, 0);
    }
  }

  #pragma unroll
  for (int nt = 0; nt < 4; ++nt) {
    const int col = nt * 16 + m;
    #pragma unroll
    for (int r = 0; r < 4; ++r)
      xp[(r0 + q * 4 + r) * DOUT + col] = acc[nt][r];
  }
}

// ---------------------------------------------------------------------------
// Kernel 2: per-node per-dim weighted median + row_sum scale + bias.
// R7: index packed into v's 5 mantissa LSBs (<=31 ulp perturbation) ->
// min/max-only sort network (2 VALU/CE instead of 5); w permuted to sorted
// order through LDS (idle pipe; bank=lane%32 -> 2-way aliasing = free).
// For non-near-tie (node,dim) [~99.98%] the sort order and thus every float
// sum is BITWISE identical to the reference (cumsum sequential in sorted
// order, total = last cum, row_sum in original edge order).
// ---------------------------------------------------------------------------
__global__ __launch_bounds__(256, 2) void median_kernel(
    const float* __restrict__ xp, const int* __restrict__ col,
    const float* __restrict__ ew, const float* __restrict__ bias,
    float* __restrict__ out) {
  __shared__ float wlds[4 * K_DEG * 64];     // [wave][j][lane], 17408 B

  const int wave = threadIdx.x >> 6;
  const int lane = threadIdx.x & 63;
  const int node = blockIdx.x * 4 + wave;
  if (node >= N_NODES) return;               // grid exact (50000 = 12500*4)

  const int*   cp = col + node * K_DEG;
  const float* wp = ew  + node * K_DEG;

  float v[K_DEG], w[K_DEG];
  #pragma unroll
  for (int j = 0; j < K_DEG; ++j) {
    int c = cp[j];
    v[j] = xp[c * DOUT + lane];              // 256B coalesced gather, pipelined
    w[j] = wp[j];
  }

  // row_sum: original edge order (matches segment_sum)
  float rs = 0.f;
  #pragma unroll
  for (int j = 0; j < K_DEG; ++j) rs += w[j];

  // stash w in LDS (own lane's column only; no cross-lane -> no barrier)
  float* wl = wlds + wave * (K_DEG * 64) + lane;
  #pragma unroll
  for (int j = 0; j < K_DEG; ++j) wl[j * 64] = w[j];

  // pack index j into the 5 mantissa LSBs of v (monotone above 31 ulps;
  // stable-by-index tie-break for positives, harmless reorder for negatives)
  #pragma unroll
  for (int j = 0; j < K_DEG; ++j) {
    union { float f; unsigned int u; } c2; c2.f = v[j];
    c2.u = (c2.u & 0xFFFFFFE0u) | (unsigned)j;
    v[j] = c2.f;
  }

  // sort v ascending — min/max-only compile-time Batcher network (2 ops/CE)
  constexpr NetArr<NP17> NET = net_pairs<NP17>(K_DEG);
  #pragma unroll
  for (int s = 0; s < NP17; ++s) {
    const int a = NET.v[s].a, b = NET.v[s].b;
    const float va = v[a], vb = v[b];
    v[a] = fminf(va, vb);
    v[b] = fmaxf(va, vb);
  }

  // recover w in sorted order: idx from LSBs -> LDS read (bank-conflict-free)
  float sw[K_DEG];
  #pragma unroll
  for (int j = 0; j < K_DEG; ++j) {
    union { float f; unsigned int u; } c2; c2.f = v[j];
    const unsigned idx = c2.u & 31u;
    sw[j] = wl[idx * 64];
  }

  // sequential cumsum in sorted order (exact reference order)
  float c[K_DEG];
  float run = 0.f;
  #pragma unroll
  for (int j = 0; j < K_DEG; ++j) { run += sw[j]; c[j] = run; }
  const float half = 0.5f * run;

  // first sorted position with cum >= half: backward cndmask scan
  float med = v[K_DEG - 1];
  #pragma unroll
  for (int j = K_DEG - 2; j >= 0; --j)
    med = (c[j] >= half) ? v[j] : med;

  out[node * DOUT + lane] = rs * med + bias[lane];
}

// ---------------------------------------------------------------------------
extern "C" void kernel_launch(void* const* d_in, const int* in_sizes, int n_in,
                              void* d_out, int out_size, void* d_ws, size_t ws_size,
                              hipStream_t stream) {
  const float* x    = (const float*)d_in[0];
  const int*   ei   = (const int*)d_in[1];
  const float* ew   = (const float*)d_in[2];
  const float* W    = (const float*)d_in[3];
  const float* bias = (const float*)d_in[4];
  float*       out  = (float*)d_out;

  float*          xp = (float*)d_ws;                            // 12.8 MB
  unsigned short* T  = (unsigned short*)((char*)d_ws + (size_t)N_NODES * DOUT * 4);
  const int*      colp = ei + (size_t)N_NODES * K_DEG;          // edge_index[1]

  convw_kernel<<<8192 / 256, 256, 0, stream>>>(W, T);
  gemm_kernel<<<(N_NODES / 16 + 3) / 4, 256, 0, stream>>>(x, T, xp);
  median_kernel<<<(N_NODES + 3) / 4, 256, 0, stream>>>(xp, colp, ew, bias, out);
}

// Round 8
// 122.304 us; speedup vs baseline: 1.0997x; 1.0250x over previous
//
#include <hip/hip_runtime.h>

#define N_NODES 50000
#define K_DEG   17
#define DIN     128
#define DOUT    64

typedef _Float16 f16;
typedef __attribute__((ext_vector_type(8))) short  short8;   // bf16 A/B frag (4 VGPR)
typedef __attribute__((ext_vector_type(4))) float  floatx4;  // C/D frag

// ---------------------------------------------------------------------------
// Batcher merge-exchange sorting network (compile-time; fully unrolls).
// ---------------------------------------------------------------------------
struct CEPair { unsigned char a, b; };

constexpr int net_count(int n) {
  int t = 0; while ((1 << t) < n) ++t;
  int cnt = 0;
  for (int p = 1 << (t - 1); p > 0; p >>= 1) {
    int q = 1 << (t - 1), r = 0, d = p;
    for (;;) {
      for (int i = 0; i < n - d; ++i)
        if ((i & p) == r) ++cnt;
      if (q == p) break;
      d = q - p; q >>= 1; r = p;
    }
  }
  return cnt;
}

template <int NP> struct NetArr { CEPair v[NP]; };

template <int NP>
constexpr NetArr<NP> net_pairs(int n) {
  NetArr<NP> out{};
  int t = 0; while ((1 << t) < n) ++t;
  int cnt = 0;
  for (int p = 1 << (t - 1); p > 0; p >>= 1) {
    int q = 1 << (t - 1), r = 0, d = p;
    for (;;) {
      for (int i = 0; i < n - d; ++i)
        if ((i & p) == r) {
          out.v[cnt].a = (unsigned char)i;
          out.v[cnt].b = (unsigned char)(i + d);
          ++cnt;
        }
      if (q == p) break;
      d = q - p; q >>= 1; r = p;
    }
  }
  return out;
}

constexpr int NP17 = net_count(K_DEG);   // 74 compare-exchanges for n=17

// ---------------------------------------------------------------------------
// bf16 helpers (RNE)
// ---------------------------------------------------------------------------
__device__ __forceinline__ unsigned int f2bf(float f) {
  union { float f; unsigned int u; } c; c.f = f;
  return (c.u + 0x7FFFu + ((c.u >> 16) & 1u)) >> 16;
}
__device__ __forceinline__ float bf2f(unsigned int b) {
  union { float f; unsigned int u; } c; c.u = b << 16;
  return c.f;
}

// ---------------------------------------------------------------------------
// Kernel 0: convert W -> frag-ordered bf16 hi/lo table T (32 KB). Frozen.
// ---------------------------------------------------------------------------
__global__ void convw_kernel(const float* __restrict__ W,
                             unsigned short* __restrict__ T) {
  const int flat = blockIdx.x * 256 + threadIdx.x;   // 0..8191
  const int j    = flat & 7;
  const int lane = (flat >> 3) & 63;
  const int pair = flat >> 9;                        // 0..15
  const int ks   = pair >> 2, nt = pair & 3;
  const int k    = ks * 32 + (lane >> 4) * 8 + j;
  const int n    = nt * 16 + (lane & 15);
  const float f  = W[k * DOUT + n];
  const unsigned int hb = f2bf(f);
  const float        lo = f - bf2f(hb);
  const unsigned int lb = f2bf(lo);
  T[flat]        = (unsigned short)hb;
  T[flat + 8192] = (unsigned short)lb;
}

// ---------------------------------------------------------------------------
// Kernel 1: xp = x @ W via bf16 MFMA, 3-term hi/lo split; fp16 output
// (halves xp store + gather bytes; fp16 rel err 2^-11 -> output
// perturbation <= ~0.01, threshold 0.3725). Structure frozen since R4.
// ---------------------------------------------------------------------------
__global__ __launch_bounds__(256) void gemm_kernel(
    const float* __restrict__ x, const unsigned short* __restrict__ T,
    f16* __restrict__ xp) {
  const int gwave = blockIdx.x * 4 + (threadIdx.x >> 6);
  if (gwave >= (N_NODES / 16)) return;
  const int lane = threadIdx.x & 63;
  const int r0 = gwave * 16;
  const int m  = lane & 15;     // A row within tile
  const int q  = lane >> 4;     // k-quad

  const float4* x4 = (const float4*)x;
  float4 xr[8];
  #pragma unroll
  for (int ks = 0; ks < 4; ++ks) {
    const int base = (r0 + m) * (DIN / 4) + ks * 8 + q * 2;
    xr[ks * 2 + 0] = x4[base + 0];
    xr[ks * 2 + 1] = x4[base + 1];
  }

  floatx4 acc[4];
  #pragma unroll
  for (int nt = 0; nt < 4; ++nt) acc[nt] = (floatx4){0.f, 0.f, 0.f, 0.f};

  const short8* Th = (const short8*)T;
  const short8* Tl = (const short8*)(T + 8192);

  #pragma unroll
  for (int ks = 0; ks < 4; ++ks) {
    short8 Bh[4], Bl[4];
    #pragma unroll
    for (int nt = 0; nt < 4; ++nt) {
      const int fi = (ks * 4 + nt) * 64 + lane;
      Bh[nt] = Th[fi];
      Bl[nt] = Tl[fi];
    }
    float f[8] = {xr[ks*2].x, xr[ks*2].y, xr[ks*2].z, xr[ks*2].w,
                  xr[ks*2+1].x, xr[ks*2+1].y, xr[ks*2+1].z, xr[ks*2+1].w};
    union { unsigned int i[4]; short8 s; } Ah, Al;
    #pragma unroll
    for (int r = 0; r < 4; ++r) {
      const unsigned int h0 = f2bf(f[2*r]),   h1 = f2bf(f[2*r+1]);
      const unsigned int l0 = f2bf(f[2*r]   - bf2f(h0));
      const unsigned int l1 = f2bf(f[2*r+1] - bf2f(h1));
      Ah.i[r] = h0 | (h1 << 16);
      Al.i[r] = l0 | (l1 << 16);
    }
    #pragma unroll
    for (int nt = 0; nt < 4; ++nt) {
      acc[nt] = __builtin_amdgcn_mfma_f32_16x16x32_bf16(Al.s, Bh[nt], acc[nt], 0, 0, 0);
      acc[nt] = __builtin_amdgcn_mfma_f32_16x16x32_bf16(Ah.s, Bl[nt], acc[nt], 0, 0, 0);
      acc[nt] = __builtin_amdgcn_mfma_f32_16x16x32_bf16(Ah.s, Bh[nt], acc[nt], 0, 0, 0);
    }
  }

  #pragma unroll
  for (int nt = 0; nt < 4; ++nt) {
    const int col = nt * 16 + m;
    #pragma unroll
    for (int r = 0; r < 4; ++r)
      xp[(r0 + q * 4 + r) * DOUT + col] = (f16)acc[nt][r];
  }
}

// ---------------------------------------------------------------------------
// Kernel 2: weighted per-dim median + row_sum scale + bias. R7 structure;
// fp16 gathers (128B/row) halve L2/L3 traffic. cvt_f32_f16 leaves 13 zero
// mantissa LSBs -> index pack is an exact v_or_b32. Exact reference
// summation order preserved (cumsum sequential in sorted order, total =
// last cum, row_sum in original edge order).
// ---------------------------------------------------------------------------
__global__ __launch_bounds__(256, 2) void median_kernel(
    const f16* __restrict__ xp, const int* __restrict__ col,
    const float* __restrict__ ew, const float* __restrict__ bias,
    float* __restrict__ out) {
  __shared__ float wlds[4 * K_DEG * 64];     // [wave][j][lane], 17408 B

  const int wave = threadIdx.x >> 6;
  const int lane = threadIdx.x & 63;
  const int node = blockIdx.x * 4 + wave;    // grid exact: 12500*4 = 50000

  const int*   cp = col + node * K_DEG;
  const float* wp = ew  + node * K_DEG;

  float v[K_DEG], w[K_DEG];
  #pragma unroll
  for (int j = 0; j < K_DEG; ++j) {
    int c = cp[j];
    v[j] = (float)xp[c * DOUT + lane];       // 128B coalesced fp16 gather
    w[j] = wp[j];
  }

  // row_sum: original edge order (matches segment_sum)
  float rs = 0.f;
  #pragma unroll
  for (int j = 0; j < K_DEG; ++j) rs += w[j];

  // stash w in LDS (own lane's column only; no cross-lane -> no barrier)
  float* wl = wlds + wave * (K_DEG * 64) + lane;
  #pragma unroll
  for (int j = 0; j < K_DEG; ++j) wl[j * 64] = w[j];

  // pack index j into mantissa LSBs (exact for fp16-sourced values)
  #pragma unroll
  for (int j = 0; j < K_DEG; ++j) {
    union { float f; unsigned int u; } c2; c2.f = v[j];
    c2.u |= (unsigned)j;
    v[j] = c2.f;
  }

  // sort v ascending — min/max-only compile-time Batcher network (2 ops/CE)
  constexpr NetArr<NP17> NET = net_pairs<NP17>(K_DEG);
  #pragma unroll
  for (int s = 0; s < NP17; ++s) {
    const int a = NET.v[s].a, b = NET.v[s].b;
    const float va = v[a], vb = v[b];
    v[a] = fminf(va, vb);
    v[b] = fmaxf(va, vb);
  }

  // recover w in sorted order: idx from LSBs -> LDS read (bank-conflict-free)
  float sw[K_DEG];
  #pragma unroll
  for (int j = 0; j < K_DEG; ++j) {
    union { float f; unsigned int u; } c2; c2.f = v[j];
    const unsigned idx = c2.u & 31u;
    sw[j] = wl[idx * 64];
  }

  // sequential cumsum in sorted order (exact reference order)
  float c[K_DEG];
  float run = 0.f;
  #pragma unroll
  for (int j = 0; j < K_DEG; ++j) { run += sw[j]; c[j] = run; }
  const float half = 0.5f * run;

  // first sorted position with cum >= half: backward cndmask scan
  float med = v[K_DEG - 1];
  #pragma unroll
  for (int j = K_DEG - 2; j >= 0; --j)
    med = (c[j] >= half) ? v[j] : med;

  out[node * DOUT + lane] = rs * med + bias[lane];
}

// ---------------------------------------------------------------------------
extern "C" void kernel_launch(void* const* d_in, const int* in_sizes, int n_in,
                              void* d_out, int out_size, void* d_ws, size_t ws_size,
                              hipStream_t stream) {
  const float* x    = (const float*)d_in[0];
  const int*   ei   = (const int*)d_in[1];
  const float* ew   = (const float*)d_in[2];
  const float* W    = (const float*)d_in[3];
  const float* bias = (const float*)d_in[4];
  float*       out  = (float*)d_out;

  f16*            xp = (f16*)d_ws;                              // 6.4 MB
  unsigned short* T  = (unsigned short*)((char*)d_ws + (size_t)N_NODES * DOUT * 2);
  const int*      colp = ei + (size_t)N_NODES * K_DEG;          // edge_index[1]

  convw_kernel<<<8192 / 256, 256, 0, stream>>>(W, T);
  gemm_kernel<<<(N_NODES / 16 + 3) / 4, 256, 0, stream>>>(x, T, xp);
  median_kernel<<<N_NODES / 4, 256, 0, stream>>>(xp, colp, ew, bias, out);
}